// Round 9
// baseline (487.688 us; speedup 1.0000x reference)
//
#include <hip/hip_runtime.h>

typedef __attribute__((ext_vector_type(8))) short short8;
typedef __attribute__((ext_vector_type(16))) float f32x16;
typedef unsigned int u32;

#define CIN   128
#define COUT  256
#define H     112
#define W     112
#define OH    110
#define OW    110
#define KHW   9
#define TH    8
#define TW    32
#define IHH   10              // TH+2
#define IWW   34              // TW+2
#define NPIX  340             // IHH*IWW
#define XB    (NPIX*8*16)     // 43520 B: x half-tile, 2720 16B slots
#define WB    16384           // w tap-half: 128 cout * 8 slots * 16B

__device__ __forceinline__ short f2b(float f) {
  unsigned u = __builtin_bit_cast(unsigned, f);
  unsigned r = (u + 0x7FFFu + ((u >> 16) & 1u)) >> 16;  // RNE
  return (short)r;
}

__device__ __forceinline__ void gload16(const void* g, void* l) {
  __builtin_amdgcn_global_load_lds(
      (const __attribute__((address_space(1))) u32*)g,
      (__attribute__((address_space(3))) u32*)l, 16, 0, 0);
}

// x LDS layout (R5/R8 measured-conflict-free): byte = p*128 + ((G^(p&7))<<4).
// DMA writes linearly (lane u -> slot u); swizzle applied on the PER-LANE
// GLOBAL SOURCE (lane u loads p=u>>3, Geff=(u&7)^(p&7)) => same involution on
// write-source and read => bijective => correct (m173).
// w LDS: byte = c*128 + ((G^(c&7))<<4), source-XOR on DMA, same on read.
// global_load_lds contract: LDS dest = readfirstlane(base) + lane*16; DMA
// issues UNCONDITIONAL across the wave (OOB -> zero page); prefix tails only.
// Inner loop: mfma_f32_32x32x16_bf16 (layouts HW-validated in R4):
//   A row=lane&31, k=(lane>>5)*8+j; B col=lane&31 (px), same k;
//   C/D col=lane&31, row=(r&3)+8*(r>>2)+4*(lane>>5).
// 2-deep fragment ring (16 VGPR/set) overlaps ds_read with MFMA in-wave.

template<bool XT, bool WT>
__global__ __launch_bounds__(512, 4)
void conv_main(const float* __restrict__ x, const float* __restrict__ wgt,
               const short* __restrict__ wt, const short* __restrict__ xt,
               const short* __restrict__ zp, float* __restrict__ out) {
  __shared__ __align__(16) char smem[XB + 2*WB];   // 76288 B -> 2 blocks/CU
  char* sx = smem;
  char* sw = smem + XB;

  const int tid = threadIdx.x;

  // XCD-chunked bijective swizzle (3584 % 8 == 0)
  const int nb  = gridDim.x;
  const int swz = (blockIdx.x & 7) * (nb >> 3) + (blockIdx.x >> 3);
  const int b    = swz / 112;            // 2 cblk * 4 tw * 14 th
  const int rem  = swz - b * 112;
  const int cblk = rem / 56;
  const int rem2 = rem - cblk * 56;
  const int t_w  = rem2 / 14;
  const int t_h  = rem2 - t_w * 14;
  const int h0 = t_h * TH, w0 = t_w * TW;

  auto stage_x = [&](int hh) {
    if (XT) {
      const short* xtb = xt + (size_t)b * (H*W*CIN);
      #pragma unroll
      for (int it = 0; it < 6; ++it) {
        int u = it*512 + tid;            // slot index, 2720 total
        if (u < 8*NPIX) {                // prefix-masked tail only: safe
          int p = u >> 3;                // pixel 0..339
          int Geff = (u & 7) ^ (p & 7);  // pre-swizzled source fragment
          int iy = p / IWW, ix = p - iy * IWW;
          int gy = h0 + iy, gx = w0 + ix;
          const short* src = (gy < H && gx < W)
              ? xtb + ((size_t)gy*W + gx)*CIN + hh*64 + Geff*8
              : zp;                      // OOB -> zero page (per-lane src ok)
          gload16(src, sx + u*16);
        }
      }
    } else {
      const float* xh = x + (size_t)b * CIN * (H*W) + (size_t)(hh*64) * (H*W);
      for (int u = tid; u < 8 * NPIX; u += 512) {
        int G = u / NPIX, p = u - G * NPIX;
        int iy = p / IWW, ix = p - iy * IWW;
        int gy = h0 + iy, gx = w0 + ix;
        short8 v = {0,0,0,0,0,0,0,0};
        if (gy < H && gx < W) {
          const float* s = xh + (size_t)(G*8) * (H*W) + gy * W + gx;
          #pragma unroll
          for (int j = 0; j < 8; ++j) v[j] = f2b(s[j * (H*W)]);
        }
        *(short8*)(sx + p*128 + ((G ^ (p & 7)) << 4)) = v;
      }
    }
  };

  auto stage_w = [&](int st, int buf) {
    int hh = st / 9, tap = st - hh * 9;
    if (WT) {
      const short* base = wt + (size_t)tap * (COUT*CIN)
                             + (size_t)(cblk*128) * CIN + hh * 64;
      #pragma unroll
      for (int it = 0; it < 2; ++it) {
        int slot = it * 512 + tid;            // 1024 slots of 16B
        int c = slot >> 3, gsw = (slot & 7) ^ (c & 7);
        gload16(base + c * CIN + gsw * 8, sw + buf*WB + slot * 16);
      }
    } else {
      #pragma unroll
      for (int it = 0; it < 2; ++it) {
        int slot = it * 512 + tid;
        int c = slot >> 3, gsw = (slot & 7) ^ (c & 7);
        int cout = cblk*128 + c;
        short8 v;
        #pragma unroll
        for (int j = 0; j < 8; ++j) {
          int cin = hh*64 + gsw*8 + j;
          v[j] = f2b(wgt[cout*(CIN*KHW) + cin*KHW + tap]);
        }
        *(short8*)(sw + buf*WB + slot * 16) = v;
      }
    }
  };

  const int lane = tid & 63;
  const int wid  = tid >> 6;
  const int wm = wid >> 2;        // 0..1 -> couts [wm*64, +64) of block's 128
  const int wn = wid & 3;         // 0..3 -> rows {2wn, 2wn+1}
  const int l31 = lane & 31;
  const int lh  = lane >> 5;      // 0/1 -> k-half of K=16

  f32x16 acc[2][2] = {};

  stage_x(0);
  stage_w(0, 0);
  __syncthreads();

  for (int st = 0; st < 18; ++st) {          // 2 cin-halves x 9 taps
    if (st + 1 < 18) stage_w(st + 1, (st + 1) & 1);

    const int tap = st % 9;
    const int kh = tap / 3, kw = tap - (tap/3)*3;
    const char* swb = sw + (st & 1) * WB;

    // per-tap loop-invariant address pieces
    const char* aptr0 = swb + (wm*64 + l31) * 128;          // mi=0 row base
    const int   asw   = l31 & 7;                            // c&7 (both mi)
    const int   prow0 = (2*wn + kh) * IWW + l31 + kw;       // ni=0 pixel
    const int   prow1 = prow0 + IWW;                        // ni=1 pixel

    short8 aA[2], bA[2], aB[2], bB[2];
    auto LDF = [&](int ks, short8* av, short8* bv) {
      const int g = ks*2 + lh;
      const int aslot = (g ^ asw) << 4;
      av[0] = *(const short8*)(aptr0 + aslot);
      av[1] = *(const short8*)(aptr0 + 32*128 + aslot);
      bv[0] = *(const short8*)(sx + prow0*128 + ((g ^ (prow0 & 7)) << 4));
      bv[1] = *(const short8*)(sx + prow1*128 + ((g ^ (prow1 & 7)) << 4));
    };
    auto MF = [&](short8* av, short8* bv) {
      #pragma unroll
      for (int mi = 0; mi < 2; ++mi)
        #pragma unroll
        for (int ni = 0; ni < 2; ++ni)
          acc[mi][ni] = __builtin_amdgcn_mfma_f32_32x32x16_bf16(
              av[mi], bv[ni], acc[mi][ni], 0, 0, 0);
    };

    LDF(0, aA, bA);            // kstep 0
    LDF(1, aB, bB);            // prefetch 1
    MF(aA, bA);                // mfma 0
    LDF(2, aA, bA);            // prefetch 2
    MF(aB, bB);                // mfma 1
    LDF(3, aB, bB);            // prefetch 3
    MF(aA, bA);                // mfma 2
    MF(aB, bB);                // mfma 3

    if (st == 8) {
      __syncthreads();      // x half-0 readers done; w(9) DMA drained here
      stage_x(1);
      __syncthreads();      // drains x half-1 DMA
    } else {
      __syncthreads();
    }
  }

  // ---- epilogue: C/D col=l31 (px), row=(r&3)+8*(r>>2)+4*lh (cout) ----
  float* ob = out + (size_t)b * COUT * (OH*OW);
  #pragma unroll
  for (int ni = 0; ni < 2; ++ni) {
    int oh = h0 + 2*wn + ni;
    int ow = w0 + l31;
    if (oh < OH && ow < OW) {
      #pragma unroll
      for (int mi = 0; mi < 2; ++mi) {
        #pragma unroll
        for (int r = 0; r < 16; ++r) {
          int crow = (r & 3) + 8*(r >> 2) + 4*lh;
          int cout = cblk*128 + wm*64 + mi*32 + crow;
          ob[(size_t)cout*(OH*OW) + oh*OW + ow] = acc[mi][ni][r];
        }
      }
    }
  }
}

// one-time weight transpose+cvt: wt[tap][cout][cin] bf16; also zeros the
// 256-B zero page that follows wt in the workspace.
__global__ void wprep(const float* __restrict__ wgt, short* __restrict__ wt,
                      short* __restrict__ zp) {
  int idx = blockIdx.x * 256 + threadIdx.x;
  if (idx < 128) zp[idx] = 0;
  if (idx >= KHW*COUT*CIN) return;
  int khw  = idx / (COUT*CIN);
  int rem  = idx - khw*(COUT*CIN);
  int cout = rem >> 7, cin = rem & 127;
  wt[idx] = f2b(wgt[cout*(CIN*KHW) + cin*KHW + khw]);
}

// one-time x transpose+cvt: xt[b][h][w][cin] bf16, via padded LDS tile.
__global__ __launch_bounds__(256)
void xprep(const float* __restrict__ x, short* __restrict__ xt) {
  __shared__ short lsh[CIN * 113];   // 28928 B
  const int bh = blockIdx.x;
  const int b = bh / H, h = bh - b * H;
  const float* src = x + ((size_t)b * CIN * H + h) * W;
  for (int u = threadIdx.x; u < CIN * W; u += 256) {
    int c = u / W, w = u - c * W;
    lsh[c * 113 + w] = f2b(src[(size_t)c * (H*W) + w]);
  }
  __syncthreads();
  short* dst = xt + (size_t)bh * (W * CIN);
  for (int o = threadIdx.x; o < W * CIN / 8; o += 256) {   // 1792
    int w = o >> 4, s = o & 15;
    short8 v;
    #pragma unroll
    for (int j = 0; j < 8; ++j) v[j] = lsh[(s*8 + j) * 113 + w];
    *(short8*)(dst + o * 8) = v;
  }
}

extern "C" void kernel_launch(void* const* d_in, const int* in_sizes, int n_in,
                              void* d_out, int out_size, void* d_ws, size_t ws_size,
                              hipStream_t stream) {
  const float* x   = (const float*)d_in[0];
  const float* wgt = (const float*)d_in[1];
  float* out = (float*)d_out;
  const size_t wt_bytes = (size_t)(KHW*COUT*CIN) * sizeof(short);   // 589824
  const size_t zp_bytes = 256;
  const size_t xt_bytes = (size_t)32 * H * W * CIN * sizeof(short); // 102.76 MB
  dim3 grid(3584);   // 2 cblk x 4 tw x 14 th x 32 b
  if (ws_size >= wt_bytes + zp_bytes + xt_bytes) {
    short* wt = (short*)d_ws;
    short* zp = (short*)((char*)d_ws + wt_bytes);
    short* xt = (short*)((char*)d_ws + wt_bytes + zp_bytes);
    wprep<<<(KHW*COUT*CIN + 255)/256, 256, 0, stream>>>(wgt, wt, zp);
    xprep<<<32 * H, 256, 0, stream>>>(x, xt);
    conv_main<true, true><<<grid, 512, 0, stream>>>(x, wgt, wt, xt, zp, out);
  } else if (ws_size >= wt_bytes + zp_bytes) {
    short* wt = (short*)d_ws;
    short* zp = (short*)((char*)d_ws + wt_bytes);
    wprep<<<(KHW*COUT*CIN + 255)/256, 256, 0, stream>>>(wgt, wt, zp);
    conv_main<false, true><<<grid, 512, 0, stream>>>(x, wgt, wt, nullptr, zp, out);
  } else {
    conv_main<false, false><<<grid, 512, 0, stream>>>(x, wgt, nullptr, nullptr, nullptr, out);
  }
}

// Round 10
// 348.052 us; speedup vs baseline: 1.4012x; 1.4012x over previous
//
#include <hip/hip_runtime.h>

typedef __attribute__((ext_vector_type(8))) short short8;
typedef __attribute__((ext_vector_type(4))) float f32x4;
typedef unsigned int u32;

#define CIN   128
#define COUT  256
#define H     112
#define W     112
#define OH    110
#define OW    110
#define KHW   9
#define TH    8
#define TW    32
#define IHH   10              // TH+2
#define IWW   34              // TW+2
#define NPIX  340             // IHH*IWW
#define XB    (NPIX*8*16)     // 43520 B: x half-tile, 2720 16B slots
#define WB    16384           // w tap-half: 128 cout * 8 slots * 16B

__device__ __forceinline__ short f2b(float f) {
  unsigned u = __builtin_bit_cast(unsigned, f);
  unsigned r = (u + 0x7FFFu + ((u >> 16) & 1u)) >> 16;  // RNE
  return (short)r;
}

__device__ __forceinline__ void gload16(const void* g, void* l) {
  __builtin_amdgcn_global_load_lds(
      (const __attribute__((address_space(1))) u32*)g,
      (__attribute__((address_space(3))) u32*)l, 16, 0, 0);
}

// x LDS layout (R5/R8 measured-conflict-free): byte = p*128 + ((G^(p&7))<<4).
// DMA writes linearly (lane u -> slot u); swizzle applied on the PER-LANE
// GLOBAL SOURCE (lane u loads p=u>>3, Geff=(u&7)^(p&7)) => same involution on
// write-source and read => bijective => correct (m173).
// w LDS: byte = c*128 + ((G^(c&7))<<4), source-XOR on DMA, same on read.
// global_load_lds contract: LDS dest = readfirstlane(base) + lane*16; DMA
// issues UNCONDITIONAL across the wave (OOB -> zero page); prefix tails only.
// R10: 256-thr blocks, wave tile 64 cout x 128 px (acc[4][8]) -> per-MFMA
// LDS read cost 0.375 b128; 2 desync'd blocks/CU overlap read/MFMA bursts.
// All LDS reads stay 16-lane (l15) 16-consecutive-p pattern = conflict-free.

template<bool XT, bool WT>
__global__ __launch_bounds__(256, 2)
void conv_main(const float* __restrict__ x, const float* __restrict__ wgt,
               const short* __restrict__ wt, const short* __restrict__ xt,
               const short* __restrict__ zp, float* __restrict__ out) {
  __shared__ __align__(16) char smem[XB + 2*WB];   // 76288 B -> 2 blocks/CU
  char* sx = smem;
  char* sw = smem + XB;

  const int tid = threadIdx.x;

  // XCD-chunked bijective swizzle (3584 % 8 == 0)
  const int nb  = gridDim.x;
  const int swz = (blockIdx.x & 7) * (nb >> 3) + (blockIdx.x >> 3);
  const int b    = swz / 112;            // 2 cblk * 4 tw * 14 th
  const int rem  = swz - b * 112;
  const int cblk = rem / 56;
  const int rem2 = rem - cblk * 56;
  const int t_w  = rem2 / 14;
  const int t_h  = rem2 - t_w * 14;
  const int h0 = t_h * TH, w0 = t_w * TW;

  auto stage_x = [&](int hh) {
    if (XT) {
      const short* xtb = xt + (size_t)b * (H*W*CIN);
      #pragma unroll
      for (int it = 0; it < 11; ++it) {
        int u = it*256 + tid;            // slot index, 2720 total
        if (u < 8*NPIX) {                // prefix-masked tail only: safe
          int p = u >> 3;                // pixel 0..339
          int Geff = (u & 7) ^ (p & 7);  // pre-swizzled source fragment
          int iy = p / IWW, ix = p - iy * IWW;
          int gy = h0 + iy, gx = w0 + ix;
          const short* src = (gy < H && gx < W)
              ? xtb + ((size_t)gy*W + gx)*CIN + hh*64 + Geff*8
              : zp;                      // OOB -> zero page (per-lane src ok)
          gload16(src, sx + u*16);
        }
      }
    } else {
      const float* xh = x + (size_t)b * CIN * (H*W) + (size_t)(hh*64) * (H*W);
      for (int u = tid; u < 8 * NPIX; u += 256) {
        int G = u / NPIX, p = u - G * NPIX;
        int iy = p / IWW, ix = p - iy * IWW;
        int gy = h0 + iy, gx = w0 + ix;
        short8 v = {0,0,0,0,0,0,0,0};
        if (gy < H && gx < W) {
          const float* s = xh + (size_t)(G*8) * (H*W) + gy * W + gx;
          #pragma unroll
          for (int j = 0; j < 8; ++j) v[j] = f2b(s[j * (H*W)]);
        }
        *(short8*)(sx + p*128 + ((G ^ (p & 7)) << 4)) = v;
      }
    }
  };

  auto stage_w = [&](int st, int buf) {
    int hh = st / 9, tap = st - hh * 9;
    if (WT) {
      const short* base = wt + (size_t)tap * (COUT*CIN)
                             + (size_t)(cblk*128) * CIN + hh * 64;
      #pragma unroll
      for (int it = 0; it < 4; ++it) {
        int slot = it * 256 + tid;            // 1024 slots of 16B
        int c = slot >> 3, gsw = (slot & 7) ^ (c & 7);
        gload16(base + c * CIN + gsw * 8, sw + buf*WB + slot * 16);
      }
    } else {
      #pragma unroll
      for (int it = 0; it < 4; ++it) {
        int slot = it * 256 + tid;
        int c = slot >> 3, gsw = (slot & 7) ^ (c & 7);
        int cout = cblk*128 + c;
        short8 v;
        #pragma unroll
        for (int j = 0; j < 8; ++j) {
          int cin = hh*64 + gsw*8 + j;
          v[j] = f2b(wgt[cout*(CIN*KHW) + cin*KHW + tap]);
        }
        *(short8*)(sw + buf*WB + slot * 16) = v;
      }
    }
  };

  const int lane = tid & 63;
  const int wid  = tid >> 6;      // 0..3
  const int wm = wid >> 1;        // 0..1 -> couts [wm*64, +64) of block's 128
  const int wn = wid & 1;         // 0..1 -> rows [wn*4, +4)
  const int l15 = lane & 15;
  const int kgrp = lane >> 4;     // 0..3

  f32x4 acc[4][8] = {};

  stage_x(0);
  stage_w(0, 0);
  __syncthreads();

  for (int st = 0; st < 18; ++st) {          // 2 cin-halves x 9 taps
    if (st + 1 < 18) stage_w(st + 1, (st + 1) & 1);

    const int tap = st % 9;
    const int kh = tap / 3, kw = tap - (tap/3)*3;
    const char* swb = sw + (st & 1) * WB;

    #pragma unroll
    for (int s = 0; s < 2; ++s) {            // two K=32 steps over 64 cins
      const int g = s*4 + kgrp;
      const int aslot = (g ^ (l15 & 7)) << 4;
      short8 a[4];
      #pragma unroll
      for (int mi = 0; mi < 4; ++mi)
        a[mi] = *(const short8*)(swb + (wm*64 + mi*16 + l15) * 128 + aslot);
      short8 bf[8];
      #pragma unroll
      for (int ni = 0; ni < 8; ++ni) {
        int p = (4*wn + (ni >> 1) + kh) * IWW + (ni & 1)*16 + l15 + kw;
        bf[ni] = *(const short8*)(sx + p*128 + ((g ^ (p & 7)) << 4));
      }
      #pragma unroll
      for (int mi = 0; mi < 4; ++mi)
        #pragma unroll
        for (int ni = 0; ni < 8; ++ni)
          acc[mi][ni] = __builtin_amdgcn_mfma_f32_16x16x32_bf16(a[mi], bf[ni], acc[mi][ni], 0, 0, 0);
    }

    if (st == 8) {
      __syncthreads();      // x half-0 readers done; w(9) DMA drained here
      stage_x(1);
      __syncthreads();      // drains x half-1 DMA
    } else {
      __syncthreads();
    }
  }

  // ---- epilogue: C layout col=l15 (px), row=4*kgrp+r (cout) [m89] ----
  float* ob = out + (size_t)b * COUT * (OH*OW);
  #pragma unroll
  for (int ni = 0; ni < 8; ++ni) {
    int oh = h0 + 4*wn + (ni >> 1);
    int ow = w0 + (ni & 1)*16 + l15;
    if (oh < OH && ow < OW) {
      #pragma unroll
      for (int mi = 0; mi < 4; ++mi) {
        #pragma unroll
        for (int r = 0; r < 4; ++r) {
          int cout = cblk*128 + wm*64 + mi*16 + kgrp*4 + r;
          ob[(size_t)cout*(OH*OW) + oh*OW + ow] = acc[mi][ni][r];
        }
      }
    }
  }
}

// one-time weight transpose+cvt: wt[tap][cout][cin] bf16; also zeros the
// 256-B zero page that follows wt in the workspace.
__global__ void wprep(const float* __restrict__ wgt, short* __restrict__ wt,
                      short* __restrict__ zp) {
  int idx = blockIdx.x * 256 + threadIdx.x;
  if (idx < 128) zp[idx] = 0;
  if (idx >= KHW*COUT*CIN) return;
  int khw  = idx / (COUT*CIN);
  int rem  = idx - khw*(COUT*CIN);
  int cout = rem >> 7, cin = rem & 127;
  wt[idx] = f2b(wgt[cout*(CIN*KHW) + cin*KHW + khw]);
}

// one-time x transpose+cvt: xt[b][h][w][cin] bf16, via padded LDS tile.
__global__ __launch_bounds__(256)
void xprep(const float* __restrict__ x, short* __restrict__ xt) {
  __shared__ short lsh[CIN * 113];   // 28928 B
  const int bh = blockIdx.x;
  const int b = bh / H, h = bh - b * H;
  const float* src = x + ((size_t)b * CIN * H + h) * W;
  for (int u = threadIdx.x; u < CIN * W; u += 256) {
    int c = u / W, w = u - c * W;
    lsh[c * 113 + w] = f2b(src[(size_t)c * (H*W) + w]);
  }
  __syncthreads();
  short* dst = xt + (size_t)bh * (W * CIN);
  for (int o = threadIdx.x; o < W * CIN / 8; o += 256) {   // 1792
    int w = o >> 4, s = o & 15;
    short8 v;
    #pragma unroll
    for (int j = 0; j < 8; ++j) v[j] = lsh[(s*8 + j) * 113 + w];
    *(short8*)(dst + o * 8) = v;
  }
}

extern "C" void kernel_launch(void* const* d_in, const int* in_sizes, int n_in,
                              void* d_out, int out_size, void* d_ws, size_t ws_size,
                              hipStream_t stream) {
  const float* x   = (const float*)d_in[0];
  const float* wgt = (const float*)d_in[1];
  float* out = (float*)d_out;
  const size_t wt_bytes = (size_t)(KHW*COUT*CIN) * sizeof(short);   // 589824
  const size_t zp_bytes = 256;
  const size_t xt_bytes = (size_t)32 * H * W * CIN * sizeof(short); // 102.76 MB
  dim3 grid(3584);   // 2 cblk x 4 tw x 14 th x 32 b
  if (ws_size >= wt_bytes + zp_bytes + xt_bytes) {
    short* wt = (short*)d_ws;
    short* zp = (short*)((char*)d_ws + wt_bytes);
    short* xt = (short*)((char*)d_ws + wt_bytes + zp_bytes);
    wprep<<<(KHW*COUT*CIN + 255)/256, 256, 0, stream>>>(wgt, wt, zp);
    xprep<<<32 * H, 256, 0, stream>>>(x, xt);
    conv_main<true, true><<<grid, 256, 0, stream>>>(x, wgt, wt, xt, zp, out);
  } else if (ws_size >= wt_bytes + zp_bytes) {
    short* wt = (short*)d_ws;
    short* zp = (short*)((char*)d_ws + wt_bytes);
    wprep<<<(KHW*COUT*CIN + 255)/256, 256, 0, stream>>>(wgt, wt, zp);
    conv_main<false, true><<<grid, 256, 0, stream>>>(x, wgt, wt, nullptr, zp, out);
  } else {
    conv_main<false, false><<<grid, 256, 0, stream>>>(x, wgt, nullptr, nullptr, nullptr, out);
  }
}

// Round 11
// 345.827 us; speedup vs baseline: 1.4102x; 1.0064x over previous
//
#include <hip/hip_runtime.h>

typedef __attribute__((ext_vector_type(8))) short short8;
typedef __attribute__((ext_vector_type(4))) float f32x4;
typedef unsigned int u32;

#define CIN   128
#define COUT  256
#define H     112
#define W     112
#define OH    110
#define OW    110
#define KHW   9
#define TH    8
#define TW    32
#define IHH   10              // TH+2
#define IWW   34              // TW+2
#define NPIX  340             // IHH*IWW
#define XB    (NPIX*8*16)     // 43520 B: x half-tile, 2720 16B slots
#define WB    16384           // w tap-half: 128 cout * 8 slots * 16B

__device__ __forceinline__ short f2b(float f) {
  unsigned u = __builtin_bit_cast(unsigned, f);
  unsigned r = (u + 0x7FFFu + ((u >> 16) & 1u)) >> 16;  // RNE
  return (short)r;
}

__device__ __forceinline__ void gload16(const void* g, void* l) {
  __builtin_amdgcn_global_load_lds(
      (const __attribute__((address_space(1))) u32*)g,
      (__attribute__((address_space(3))) u32*)l, 16, 0, 0);
}

// x LDS layout (R5/R8 measured-conflict-free): byte = p*128 + ((G^(p&7))<<4).
// DMA writes linearly (lane u -> slot u); swizzle applied on the PER-LANE
// GLOBAL SOURCE (lane u loads p=u>>3, Geff=(u&7)^(p&7)) => same involution on
// write-source and read => bijective => correct (m173).
// w LDS: byte = c*128 + ((G^(c&7))<<4), source-XOR on DMA, same on read.
// global_load_lds contract: LDS dest = readfirstlane(base) + lane*16; DMA
// issues UNCONDITIONAL across the wave (OOB -> zero page); prefix tails only.
// R11: 4 sub-phases per tap {reads -> setprio(1) MFMA cluster}, T5-style;
// 16-lane (l15) read patterns only (32-lane has structural 4-way conflicts).

template<bool XT, bool WT>
__global__ __launch_bounds__(256, 2)
void conv_main(const float* __restrict__ x, const float* __restrict__ wgt,
               const short* __restrict__ wt, const short* __restrict__ xt,
               const short* __restrict__ zp, float* __restrict__ out) {
  __shared__ __align__(16) char smem[XB + 2*WB];   // 76288 B -> 2 blocks/CU
  char* sx = smem;
  char* sw = smem + XB;

  const int tid = threadIdx.x;

  // XCD-chunked bijective swizzle (3584 % 8 == 0)
  const int nb  = gridDim.x;
  const int swz = (blockIdx.x & 7) * (nb >> 3) + (blockIdx.x >> 3);
  const int b    = swz / 112;            // 2 cblk * 4 tw * 14 th
  const int rem  = swz - b * 112;
  const int cblk = rem / 56;
  const int rem2 = rem - cblk * 56;
  const int t_w  = rem2 / 14;
  const int t_h  = rem2 - t_w * 14;
  const int h0 = t_h * TH, w0 = t_w * TW;

  auto stage_x = [&](int hh) {
    if (XT) {
      const short* xtb = xt + (size_t)b * (H*W*CIN);
      #pragma unroll
      for (int it = 0; it < 11; ++it) {
        int u = it*256 + tid;            // slot index, 2720 total
        if (u < 8*NPIX) {                // prefix-masked tail only: safe
          int p = u >> 3;                // pixel 0..339
          int Geff = (u & 7) ^ (p & 7);  // pre-swizzled source fragment
          int iy = p / IWW, ix = p - iy * IWW;
          int gy = h0 + iy, gx = w0 + ix;
          const short* src = (gy < H && gx < W)
              ? xtb + ((size_t)gy*W + gx)*CIN + hh*64 + Geff*8
              : zp;                      // OOB -> zero page (per-lane src ok)
          gload16(src, sx + u*16);
        }
      }
    } else {
      const float* xh = x + (size_t)b * CIN * (H*W) + (size_t)(hh*64) * (H*W);
      for (int u = tid; u < 8 * NPIX; u += 256) {
        int G = u / NPIX, p = u - G * NPIX;
        int iy = p / IWW, ix = p - iy * IWW;
        int gy = h0 + iy, gx = w0 + ix;
        short8 v = {0,0,0,0,0,0,0,0};
        if (gy < H && gx < W) {
          const float* s = xh + (size_t)(G*8) * (H*W) + gy * W + gx;
          #pragma unroll
          for (int j = 0; j < 8; ++j) v[j] = f2b(s[j * (H*W)]);
        }
        *(short8*)(sx + p*128 + ((G ^ (p & 7)) << 4)) = v;
      }
    }
  };

  auto stage_w = [&](int st, int buf) {
    int hh = st / 9, tap = st - hh * 9;
    if (WT) {
      const short* base = wt + (size_t)tap * (COUT*CIN)
                             + (size_t)(cblk*128) * CIN + hh * 64;
      #pragma unroll
      for (int it = 0; it < 4; ++it) {
        int slot = it * 256 + tid;            // 1024 slots of 16B
        int c = slot >> 3, gsw = (slot & 7) ^ (c & 7);
        gload16(base + c * CIN + gsw * 8, sw + buf*WB + slot * 16);
      }
    } else {
      #pragma unroll
      for (int it = 0; it < 4; ++it) {
        int slot = it * 256 + tid;
        int c = slot >> 3, gsw = (slot & 7) ^ (c & 7);
        int cout = cblk*128 + c;
        short8 v;
        #pragma unroll
        for (int j = 0; j < 8; ++j) {
          int cin = hh*64 + gsw*8 + j;
          v[j] = f2b(wgt[cout*(CIN*KHW) + cin*KHW + tap]);
        }
        *(short8*)(sw + buf*WB + slot * 16) = v;
      }
    }
  };

  const int lane = tid & 63;
  const int wid  = tid >> 6;      // 0..3
  const int wm = wid >> 1;        // 0..1 -> couts [wm*64, +64) of block's 128
  const int wn = wid & 1;         // 0..1 -> rows [wn*4, +4)
  const int l15 = lane & 15;
  const int kgrp = lane >> 4;     // 0..3

  f32x4 acc[4][8] = {};

  stage_x(0);
  stage_w(0, 0);
  __syncthreads();

  for (int st = 0; st < 18; ++st) {          // 2 cin-halves x 9 taps
    if (st + 1 < 18) stage_w(st + 1, (st + 1) & 1);

    const int tap = st % 9;
    const int kh = tap / 3, kw = tap - (tap/3)*3;
    const char* swb = sw + (st & 1) * WB;

    #pragma unroll
    for (int s = 0; s < 2; ++s) {            // two K=32 steps over 64 cins
      const int g = s*4 + kgrp;
      const int aslot = (g ^ (l15 & 7)) << 4;
      short8 a[4];
      #pragma unroll
      for (int mi = 0; mi < 4; ++mi)
        a[mi] = *(const short8*)(swb + (wm*64 + mi*16 + l15) * 128 + aslot);

      short8 bf[4];
      // ---- sub-phase A: ni 0..3 ----
      #pragma unroll
      for (int ni = 0; ni < 4; ++ni) {
        int p = (4*wn + (ni >> 1) + kh) * IWW + (ni & 1)*16 + l15 + kw;
        bf[ni] = *(const short8*)(sx + p*128 + ((g ^ (p & 7)) << 4));
      }
      __builtin_amdgcn_s_setprio(1);
      #pragma unroll
      for (int mi = 0; mi < 4; ++mi)
        #pragma unroll
        for (int ni = 0; ni < 4; ++ni)
          acc[mi][ni] = __builtin_amdgcn_mfma_f32_16x16x32_bf16(a[mi], bf[ni], acc[mi][ni], 0, 0, 0);
      __builtin_amdgcn_s_setprio(0);

      // ---- sub-phase B: ni 4..7 (reuse bf regs) ----
      #pragma unroll
      for (int ni = 0; ni < 4; ++ni) {
        int p = (4*wn + 2 + (ni >> 1) + kh) * IWW + (ni & 1)*16 + l15 + kw;
        bf[ni] = *(const short8*)(sx + p*128 + ((g ^ (p & 7)) << 4));
      }
      __builtin_amdgcn_s_setprio(1);
      #pragma unroll
      for (int mi = 0; mi < 4; ++mi)
        #pragma unroll
        for (int ni = 0; ni < 4; ++ni)
          acc[mi][ni + 4] = __builtin_amdgcn_mfma_f32_16x16x32_bf16(a[mi], bf[ni], acc[mi][ni + 4], 0, 0, 0);
      __builtin_amdgcn_s_setprio(0);
    }

    if (st == 8) {
      __syncthreads();      // x half-0 readers done; w(9) DMA drained here
      stage_x(1);
      __syncthreads();      // drains x half-1 DMA
    } else {
      __syncthreads();
    }
  }

  // ---- epilogue: C layout col=l15 (px), row=4*kgrp+r (cout) [m89] ----
  float* ob = out + (size_t)b * COUT * (OH*OW);
  #pragma unroll
  for (int ni = 0; ni < 8; ++ni) {
    int oh = h0 + 4*wn + (ni >> 1);
    int ow = w0 + (ni & 1)*16 + l15;
    if (oh < OH && ow < OW) {
      #pragma unroll
      for (int mi = 0; mi < 4; ++mi) {
        #pragma unroll
        for (int r = 0; r < 4; ++r) {
          int cout = cblk*128 + wm*64 + mi*16 + kgrp*4 + r;
          ob[(size_t)cout*(OH*OW) + oh*OW + ow] = acc[mi][ni][r];
        }
      }
    }
  }
}

// one-time weight transpose+cvt: wt[tap][cout][cin] bf16; also zeros the
// 256-B zero page that follows wt in the workspace.
__global__ void wprep(const float* __restrict__ wgt, short* __restrict__ wt,
                      short* __restrict__ zp) {
  int idx = blockIdx.x * 256 + threadIdx.x;
  if (idx < 128) zp[idx] = 0;
  if (idx >= KHW*COUT*CIN) return;
  int khw  = idx / (COUT*CIN);
  int rem  = idx - khw*(COUT*CIN);
  int cout = rem >> 7, cin = rem & 127;
  wt[idx] = f2b(wgt[cout*(CIN*KHW) + cin*KHW + khw]);
}

// one-time x transpose+cvt: xt[b][h][w][cin] bf16, via padded LDS tile.
__global__ __launch_bounds__(256)
void xprep(const float* __restrict__ x, short* __restrict__ xt) {
  __shared__ short lsh[CIN * 113];   // 28928 B
  const int bh = blockIdx.x;
  const int b = bh / H, h = bh - b * H;
  const float* src = x + ((size_t)b * CIN * H + h) * W;
  for (int u = threadIdx.x; u < CIN * W; u += 256) {
    int c = u / W, w = u - c * W;
    lsh[c * 113 + w] = f2b(src[(size_t)c * (H*W) + w]);
  }
  __syncthreads();
  short* dst = xt + (size_t)bh * (W * CIN);
  for (int o = threadIdx.x; o < W * CIN / 8; o += 256) {   // 1792
    int w = o >> 4, s = o & 15;
    short8 v;
    #pragma unroll
    for (int j = 0; j < 8; ++j) v[j] = lsh[(s*8 + j) * 113 + w];
    *(short8*)(dst + o * 8) = v;
  }
}

extern "C" void kernel_launch(void* const* d_in, const int* in_sizes, int n_in,
                              void* d_out, int out_size, void* d_ws, size_t ws_size,
                              hipStream_t stream) {
  const float* x   = (const float*)d_in[0];
  const float* wgt = (const float*)d_in[1];
  float* out = (float*)d_out;
  const size_t wt_bytes = (size_t)(KHW*COUT*CIN) * sizeof(short);   // 589824
  const size_t zp_bytes = 256;
  const size_t xt_bytes = (size_t)32 * H * W * CIN * sizeof(short); // 102.76 MB
  dim3 grid(3584);   // 2 cblk x 4 tw x 14 th x 32 b
  if (ws_size >= wt_bytes + zp_bytes + xt_bytes) {
    short* wt = (short*)d_ws;
    short* zp = (short*)((char*)d_ws + wt_bytes);
    short* xt = (short*)((char*)d_ws + wt_bytes + zp_bytes);
    wprep<<<(KHW*COUT*CIN + 255)/256, 256, 0, stream>>>(wgt, wt, zp);
    xprep<<<32 * H, 256, 0, stream>>>(x, xt);
    conv_main<true, true><<<grid, 256, 0, stream>>>(x, wgt, wt, xt, zp, out);
  } else if (ws_size >= wt_bytes + zp_bytes) {
    short* wt = (short*)d_ws;
    short* zp = (short*)((char*)d_ws + wt_bytes);
    wprep<<<(KHW*COUT*CIN + 255)/256, 256, 0, stream>>>(wgt, wt, zp);
    conv_main<false, true><<<grid, 256, 0, stream>>>(x, wgt, wt, nullptr, zp, out);
  } else {
    conv_main<false, false><<<grid, 256, 0, stream>>>(x, wgt, nullptr, nullptr, nullptr, out);
  }
}